// Round 3
// baseline (231.667 us; speedup 1.0000x reference)
//
#include <hip/hip_runtime.h>
#include <math.h>

// Deformation4D: N=1M gaussians, K_NB=10, K_TOTAL=300 control points.
// R3: compressed 8-float LDS records {qhat(4), |q|(1), b(3)} at 12-dword
// stride (8 bank start-groups); rotate by quaternion in registers instead of
// reading a 9-float R. Halves ds_read_b128 count per neighbor (4 -> 2).
// Persistent grid (512 blocks, grid-stride chunks) amortizes table build
// 1953 -> 512 and gives per-thread ILP via next-chunk prefetch.
//
// dm   = sum_k w_k * (rot(qhat_k, m) + b_k),  b_k = p_k + t_k - rot(qhat_k, p_k)
// qacc = sum_k (w_k * n_k) * qhat_k          (n*qhat == raw ctrl quat)

__device__ __forceinline__ float3 quat_rotate(float qw, float qx, float qy, float qz,
                                              float vx, float vy, float vz) {
    // v' = v + qw*t + cross(qv, t),  t = 2*cross(qv, v)
    float cx = qy * vz - qz * vy;
    float cy = qz * vx - qx * vz;
    float cz = qx * vy - qy * vx;
    float tx = cx + cx, ty = cy + cy, tz = cz + cz;
    float rx = fmaf(qy, tz, fmaf(-qz, ty, fmaf(qw, tx, vx)));
    float ry = fmaf(qz, tx, fmaf(-qx, tz, fmaf(qw, ty, vy)));
    float rz = fmaf(qx, ty, fmaf(-qy, tx, fmaf(qw, tz, vz)));
    return make_float3(rx, ry, rz);
}

template <int KNB>
__global__ __launch_bounds__(512, 4) void deform_kernel(
    const float* __restrict__ means,
    const float* __restrict__ quats,
    const float* __restrict__ weights,
    const float* __restrict__ ctrl_trans,
    const float* __restrict__ ctrl_rot,
    const float* __restrict__ ctrl_pos,
    const int*   __restrict__ indices,
    float* __restrict__ out_means,
    float* __restrict__ out_quats,
    int N, int K_TOTAL)
{
    extern __shared__ float4 sT[];   // record cp: sT[cp*3+0]=qhat, sT[cp*3+1]=(n,bx,by,bz)

    const long long gstride = (long long)gridDim.x * blockDim.x;
    long long i = (long long)blockIdx.x * blockDim.x + threadIdx.x;
    bool act = i < N;

    // ---- prefetch chunk 0 (loads in flight across the table build) ----
    int   idx[KNB];
    float wt[KNB];
    float mx = 0.f, my = 0.f, mz = 0.f;
    float4 g = make_float4(0.f, 0.f, 0.f, 0.f);
    if (act) {
        const int2*   ip = (const int2*)(indices + i * KNB);
        const float2* wp = (const float2*)(weights + i * KNB);
#pragma unroll
        for (int k = 0; k < KNB / 2; k++) {
            int2 iv = ip[k]; float2 wv = wp[k];
            idx[2 * k] = iv.x; idx[2 * k + 1] = iv.y;
            wt[2 * k] = wv.x;  wt[2 * k + 1] = wv.y;
        }
        if (KNB & 1) { idx[KNB-1] = indices[i*KNB + KNB-1]; wt[KNB-1] = weights[i*KNB + KNB-1]; }
        mx = means[i * 3 + 0]; my = means[i * 3 + 1]; mz = means[i * 3 + 2];
        g = ((const float4*)quats)[i];
    }

    // ---- build compressed control-point table ----
    for (int cp = threadIdx.x; cp < K_TOTAL; cp += blockDim.x) {
        float4 q = ((const float4*)ctrl_rot)[cp];
        float n   = sqrtf(q.x*q.x + q.y*q.y + q.z*q.z + q.w*q.w);
        float inv = 1.0f / fmaxf(n, 1e-8f);
        float qw = q.x*inv, qx = q.y*inv, qy = q.z*inv, qz = q.w*inv;
        float px = ctrl_pos[cp*3+0], py = ctrl_pos[cp*3+1], pz = ctrl_pos[cp*3+2];
        float tx = ctrl_trans[cp*3+0], ty = ctrl_trans[cp*3+1], tz = ctrl_trans[cp*3+2];
        float3 rp = quat_rotate(qw, qx, qy, qz, px, py, pz);
        float bx = px + tx - rp.x;
        float by = py + ty - rp.y;
        float bz = pz + tz - rp.z;
        sT[cp * 3 + 0] = make_float4(qw, qx, qy, qz);
        sT[cp * 3 + 1] = make_float4(n, bx, by, bz);
    }
    __syncthreads();

    // ---- grid-stride chunks with next-chunk prefetch ----
    while (act) {
        long long inext = i + gstride;
        bool actn = inext < N;

        int   idx2[KNB];
        float wt2[KNB];
        float mx2 = 0.f, my2 = 0.f, mz2 = 0.f;
        float4 g2 = make_float4(0.f, 0.f, 0.f, 0.f);
        if (actn) {
            const int2*   ip = (const int2*)(indices + inext * KNB);
            const float2* wp = (const float2*)(weights + inext * KNB);
#pragma unroll
            for (int k = 0; k < KNB / 2; k++) {
                int2 iv = ip[k]; float2 wv = wp[k];
                idx2[2 * k] = iv.x; idx2[2 * k + 1] = iv.y;
                wt2[2 * k] = wv.x;  wt2[2 * k + 1] = wv.y;
            }
            if (KNB & 1) { idx2[KNB-1] = indices[inext*KNB + KNB-1]; wt2[KNB-1] = weights[inext*KNB + KNB-1]; }
            mx2 = means[inext * 3 + 0]; my2 = means[inext * 3 + 1]; mz2 = means[inext * 3 + 2];
            g2 = ((const float4*)quats)[inext];
        }

        float dmx = 0.f, dmy = 0.f, dmz = 0.f;
        float qaw = 0.f, qax = 0.f, qay = 0.f, qaz = 0.f;

#pragma unroll
        for (int k = 0; k < KNB; k++) {
            int   cp = idx[k];
            float w  = wt[k];
            float4 qh = sT[cp * 3 + 0];   // qw qx qy qz (normalized)
            float4 nb = sT[cp * 3 + 1];   // n  bx by bz
            float3 r  = quat_rotate(qh.x, qh.y, qh.z, qh.w, mx, my, mz);
            dmx = fmaf(w, r.x + nb.y, dmx);
            dmy = fmaf(w, r.y + nb.z, dmy);
            dmz = fmaf(w, r.z + nb.w, dmz);
            float wn = w * nb.x;
            qaw = fmaf(wn, qh.x, qaw);
            qax = fmaf(wn, qh.y, qax);
            qay = fmaf(wn, qh.z, qay);
            qaz = fmaf(wn, qh.w, qaz);
        }

        // epilogue for chunk i
        out_means[i * 3 + 0] = dmx;
        out_means[i * 3 + 1] = dmy;
        out_means[i * 3 + 2] = dmz;

        float n   = sqrtf(qaw*qaw + qax*qax + qay*qay + qaz*qaz);
        float inv = 1.0f / fmaxf(n, 1e-8f);
        float bw = qaw*inv, bx = qax*inv, by = qay*inv, bz = qaz*inv;
        float gw = g.x, gx = g.y, gy = g.z, gz = g.w;
        float ow = bw*gw - bx*gx - by*gy - bz*gz;
        float ox = bw*gx + bx*gw + by*gz - bz*gy;
        float oy = bw*gy - bx*gz + by*gw + bz*gx;
        float oz = bw*gz + bx*gy - by*gx + bz*gw;
        ((float4*)out_quats)[i] = make_float4(ow, ox, oy, oz);

        // rotate prefetched chunk in
#pragma unroll
        for (int k = 0; k < KNB; k++) { idx[k] = idx2[k]; wt[k] = wt2[k]; }
        mx = mx2; my = my2; mz = mz2; g = g2;
        i = inext; act = actn;
    }
}

// generic fallback (runtime K_NB) — correctness path only
__global__ __launch_bounds__(512, 4) void deform_kernel_generic(
    const float* __restrict__ means,
    const float* __restrict__ quats,
    const float* __restrict__ weights,
    const float* __restrict__ ctrl_trans,
    const float* __restrict__ ctrl_rot,
    const float* __restrict__ ctrl_pos,
    const int*   __restrict__ indices,
    float* __restrict__ out_means,
    float* __restrict__ out_quats,
    int N, int K_NB, int K_TOTAL)
{
    extern __shared__ float4 sT[];
    for (int cp = threadIdx.x; cp < K_TOTAL; cp += blockDim.x) {
        float4 q = ((const float4*)ctrl_rot)[cp];
        float n   = sqrtf(q.x*q.x + q.y*q.y + q.z*q.z + q.w*q.w);
        float inv = 1.0f / fmaxf(n, 1e-8f);
        float qw = q.x*inv, qx = q.y*inv, qy = q.z*inv, qz = q.w*inv;
        float px = ctrl_pos[cp*3+0], py = ctrl_pos[cp*3+1], pz = ctrl_pos[cp*3+2];
        float tx = ctrl_trans[cp*3+0], ty = ctrl_trans[cp*3+1], tz = ctrl_trans[cp*3+2];
        float3 rp = quat_rotate(qw, qx, qy, qz, px, py, pz);
        sT[cp * 3 + 0] = make_float4(qw, qx, qy, qz);
        sT[cp * 3 + 1] = make_float4(n, px + tx - rp.x, py + ty - rp.y, pz + tz - rp.z);
    }
    __syncthreads();

    long long i = (long long)blockIdx.x * blockDim.x + threadIdx.x;
    if (i >= N) return;

    float mx = means[i*3+0], my = means[i*3+1], mz = means[i*3+2];
    float dmx = 0.f, dmy = 0.f, dmz = 0.f;
    float qaw = 0.f, qax = 0.f, qay = 0.f, qaz = 0.f;
    for (int k = 0; k < K_NB; k++) {
        int   cp = indices[i * K_NB + k];
        float w  = weights[i * K_NB + k];
        float4 qh = sT[cp * 3 + 0];
        float4 nb = sT[cp * 3 + 1];
        float3 r  = quat_rotate(qh.x, qh.y, qh.z, qh.w, mx, my, mz);
        dmx = fmaf(w, r.x + nb.y, dmx);
        dmy = fmaf(w, r.y + nb.z, dmy);
        dmz = fmaf(w, r.z + nb.w, dmz);
        float wn = w * nb.x;
        qaw = fmaf(wn, qh.x, qaw); qax = fmaf(wn, qh.y, qax);
        qay = fmaf(wn, qh.z, qay); qaz = fmaf(wn, qh.w, qaz);
    }
    out_means[i*3+0] = dmx; out_means[i*3+1] = dmy; out_means[i*3+2] = dmz;
    float n   = sqrtf(qaw*qaw + qax*qax + qay*qay + qaz*qaz);
    float inv = 1.0f / fmaxf(n, 1e-8f);
    float bw = qaw*inv, bx = qax*inv, by = qay*inv, bz = qaz*inv;
    float4 gq = ((const float4*)quats)[i];
    float gw = gq.x, gx = gq.y, gy = gq.z, gz = gq.w;
    ((float4*)out_quats)[i] = make_float4(
        bw*gw - bx*gx - by*gy - bz*gz,
        bw*gx + bx*gw + by*gz - bz*gy,
        bw*gy - bx*gz + by*gw + bz*gx,
        bw*gz + bx*gy - by*gx + bz*gw);
}

extern "C" void kernel_launch(void* const* d_in, const int* in_sizes, int n_in,
                              void* d_out, int out_size, void* d_ws, size_t ws_size,
                              hipStream_t stream) {
    const float* means      = (const float*)d_in[0];
    const float* quats      = (const float*)d_in[1];
    const float* weights    = (const float*)d_in[2];
    const float* ctrl_trans = (const float*)d_in[3];
    const float* ctrl_rot   = (const float*)d_in[4];
    const float* ctrl_pos   = (const float*)d_in[5];
    const int*   indices    = (const int*)d_in[6];

    int N       = in_sizes[0] / 3;
    int K_NB    = in_sizes[2] / N;
    int K_TOTAL = in_sizes[3] / 3;

    float* out_means = (float*)d_out;
    float* out_quats = (float*)d_out + (long long)N * 3;

    const int block = 512;
    size_t smem = (size_t)K_TOTAL * 3 * sizeof(float4);

    if (K_NB == 10 || K_NB == 8 || K_NB == 16 || K_NB == 4 || K_NB == 6 || K_NB == 12) {
        // persistent grid: 2 blocks per CU; grid-stride covers N
        int grid = 512;
        int needed = (int)((N + (long long)block - 1) / block);
        if (needed < grid) grid = needed;
        switch (K_NB) {
        case 4:  deform_kernel<4 ><<<grid, block, smem, stream>>>(means, quats, weights, ctrl_trans, ctrl_rot, ctrl_pos, indices, out_means, out_quats, N, K_TOTAL); break;
        case 6:  deform_kernel<6 ><<<grid, block, smem, stream>>>(means, quats, weights, ctrl_trans, ctrl_rot, ctrl_pos, indices, out_means, out_quats, N, K_TOTAL); break;
        case 8:  deform_kernel<8 ><<<grid, block, smem, stream>>>(means, quats, weights, ctrl_trans, ctrl_rot, ctrl_pos, indices, out_means, out_quats, N, K_TOTAL); break;
        case 10: deform_kernel<10><<<grid, block, smem, stream>>>(means, quats, weights, ctrl_trans, ctrl_rot, ctrl_pos, indices, out_means, out_quats, N, K_TOTAL); break;
        case 12: deform_kernel<12><<<grid, block, smem, stream>>>(means, quats, weights, ctrl_trans, ctrl_rot, ctrl_pos, indices, out_means, out_quats, N, K_TOTAL); break;
        case 16: deform_kernel<16><<<grid, block, smem, stream>>>(means, quats, weights, ctrl_trans, ctrl_rot, ctrl_pos, indices, out_means, out_quats, N, K_TOTAL); break;
        }
    } else {
        int grid = (int)((N + (long long)block - 1) / block);
        deform_kernel_generic<<<grid, block, smem, stream>>>(
            means, quats, weights, ctrl_trans, ctrl_rot, ctrl_pos, indices,
            out_means, out_quats, N, K_NB, K_TOTAL);
    }
}